// Round 5
// baseline (229.823 us; speedup 1.0000x reference)
//
#include <hip/hip_runtime.h>
#include <hip/hip_bf16.h>
#include <math.h>

#define NN 1024
#define KJ 32                 // j per chunk
#define NCHUNK (NN / KJ)      // 32
#define LP 40                 // LDS row pitch in ushorts (80 B, 16B-aligned)

typedef __attribute__((ext_vector_type(8))) short v8s;
typedef __attribute__((ext_vector_type(4))) float v4f;

#define MFMA(a, b, c) __builtin_amdgcn_mfma_f32_16x16x32_bf16((a), (b), (c), 0, 0, 0)

static __device__ __forceinline__ float silu_f(float x) {
    return x / (1.0f + __expf(-x));
}
static __device__ __forceinline__ unsigned short f2bf(float x) {
    __hip_bfloat16 h = __float2bfloat16(x);
    unsigned short u; __builtin_memcpy(&u, &h, 2); return u;
}
static __device__ __forceinline__ unsigned pack2bf(float lo, float hi) {
    __hip_bfloat162 h = __float22bfloat162_rn(make_float2(lo, hi));
    unsigned u; __builtin_memcpy(&u, &h, 4); return u;
}

// ---------------------------------------------------------------------------
// Kernel 1: per-node precompute -> RT[160][1024] bf16 (n-major, j contiguous).
// rows 0..31: lB[f]; 32..127: P[d,f]=v[j,d,f]*lA[f]; 128..159: lC[f].
// ---------------------------------------------------------------------------
extern "C" __global__ __launch_bounds__(128)
void node_kernel(const float* __restrict__ scalar,
                 const float* __restrict__ vector,
                 const float* __restrict__ mL_w1, const float* __restrict__ mL_b1,
                 const float* __restrict__ mL_w2, const float* __restrict__ mL_b2,
                 unsigned short* __restrict__ RT)
{
    const int j = blockIdx.x;
    const int t = threadIdx.x;
    __shared__ float ss[32], sh[32], sleft[96];

    if (t < 32) ss[t] = scalar[j * 32 + t];
    __syncthreads();
    if (t < 32) {
        float a = mL_b1[t];
        #pragma unroll
        for (int k = 0; k < 32; k++) a = fmaf(ss[k], mL_w1[k * 32 + t], a);
        sh[t] = silu_f(a);
    }
    __syncthreads();
    if (t < 96) {
        float a = mL_b2[t];
        #pragma unroll
        for (int k = 0; k < 32; k++) a = fmaf(sh[k], mL_w2[k * 96 + t], a);
        sleft[t] = a;
    }
    __syncthreads();
    for (int n = t; n < 160; n += 128) {
        float val;
        if (n < 32)        val = sleft[32 + n];
        else if (n < 128)  val = vector[j * 96 + (n - 32)] * sleft[(n - 32) & 31];
        else               val = sleft[64 + (n - 128)];
        RT[(size_t)n * NN + j] = f2bf(val);
    }
}

// ---------------------------------------------------------------------------
// Kernel 2: barrier-free wave-specialized MFMA + fused epilogue. 1 block/i.
// wave0: T1 (M=21pad32, N=128) from private L1; wave1: T2 (M=63pad64, N=32)
// from private L2. Garbage pad rows land in unread output rows.
// ---------------------------------------------------------------------------
extern "C" __global__ __launch_bounds__(128, 3)
void edge_mfma_kernel(const float* __restrict__ scalar,
                      const float* __restrict__ vector,
                      const float* __restrict__ expansion,
                      const float* __restrict__ direction,
                      const float* __restrict__ mask,
                      const float* __restrict__ mR_w, const float* __restrict__ mR_b,
                      const float* __restrict__ uR_w1, const float* __restrict__ uR_b1,
                      const float* __restrict__ uR_w2, const float* __restrict__ uR_b2,
                      const float* __restrict__ U_w,  const float* __restrict__ V_w,
                      const unsigned short* __restrict__ RT,
                      float* __restrict__ out)
{
    const int i = blockIdx.x;
    const int t = threadIdx.x;
    const int wave = t >> 6;
    const int lane = t & 63;
    const int lrow = lane & 15;
    const int quad = lane >> 4;
    const int jp = lane >> 2;      // 0..15 (j-pair slot)
    const int g  = lane & 3;       // row-group
    const int jl = jp * 2;

    // build buffers (bf16) overlaid by compact T (fp32) after the main loop
    __shared__ __align__(16) char smem[18944];
    unsigned short* L1 = (unsigned short*)smem;            // [32][LP]
    unsigned short* L2 = (unsigned short*)(smem + 2560);   // [64][LP]
    float* T1c = (float*)smem;                             // [21][128]
    float* T2c = (float*)(smem + 10752);                   // [63][32]
    __shared__ float snew[32], vnew[96], lUs[96], rVs[96], rnorm[32], h2s[32], f2s[96];

    v4f acc[16];
    #pragma unroll
    for (int q = 0; q < 16; ++q) acc[q] = (v4f){0.f, 0.f, 0.f, 0.f};

    if (wave == 0) {
        // ---- T1 wave: L1 rows = m*exp (e=0..19), row 20 = m ----
        for (int ch = 0; ch < NCHUNK; ++ch) {
            const int j0 = ch * KJ;
            const size_t jg = (size_t)i * NN + j0 + jl;
            const float4 fa = *(const float4*)(expansion + jg * 20 + 4 * g);
            const float4 fb = *(const float4*)(expansion + (jg + 1) * 20 + 4 * g);
            const float m0 = mask[jg], m1 = mask[jg + 1];
            {
                const float ea[4] = {fa.x, fa.y, fa.z, fa.w};
                const float eb[4] = {fb.x, fb.y, fb.z, fb.w};
                #pragma unroll
                for (int k = 0; k < 4; ++k)
                    *(unsigned*)(L1 + (4 * g + k) * LP + jl) = pack2bf(m0 * ea[k], m1 * eb[k]);
            }
            if (g == 3) {   // q4 rows e=16..19
                const float4 ca = *(const float4*)(expansion + jg * 20 + 16);
                const float4 cb = *(const float4*)(expansion + (jg + 1) * 20 + 16);
                const float ea[4] = {ca.x, ca.y, ca.z, ca.w};
                const float eb[4] = {cb.x, cb.y, cb.z, cb.w};
                #pragma unroll
                for (int k = 0; k < 4; ++k)
                    *(unsigned*)(L1 + (16 + k) * LP + jl) = pack2bf(m0 * ea[k], m1 * eb[k]);
            }
            if (g == 0) *(unsigned*)(L1 + 20 * LP + jl) = pack2bf(m0, m1);

            const int koff = quad * 8;
            const v8s a0 = *(const v8s*)(L1 + lrow * LP + koff);
            const v8s a1 = *(const v8s*)(L1 + (16 + lrow) * LP + koff);
            const unsigned short* Bp = RT + (size_t)lrow * NN + j0 + koff;
            #pragma unroll
            for (int nt = 0; nt < 8; ++nt) {
                const v8s b = *(const v8s*)(Bp + (size_t)nt * 16 * NN);
                acc[nt]     = MFMA(a0, b, acc[nt]);
                acc[8 + nt] = MFMA(a1, b, acc[8 + nt]);
            }
        }
    } else {
        // ---- T2 wave: L2 rows d*20+e = m*dir_d*exp_e, rows 60..62 = m*dir_d ----
        for (int ch = 0; ch < NCHUNK; ++ch) {
            const int j0 = ch * KJ;
            const size_t jg = (size_t)i * NN + j0 + jl;
            const float m0 = mask[jg], m1 = mask[jg + 1];
            const float pa[3] = {m0 * direction[jg * 3 + 0],
                                 m0 * direction[jg * 3 + 1],
                                 m0 * direction[jg * 3 + 2]};
            const float pb[3] = {m1 * direction[(jg + 1) * 3 + 0],
                                 m1 * direction[(jg + 1) * 3 + 1],
                                 m1 * direction[(jg + 1) * 3 + 2]};
            const float4 fa = *(const float4*)(expansion + jg * 20 + 4 * g);
            const float4 fb = *(const float4*)(expansion + (jg + 1) * 20 + 4 * g);
            const float ea[4] = {fa.x, fa.y, fa.z, fa.w};
            const float eb[4] = {fb.x, fb.y, fb.z, fb.w};
            #pragma unroll
            for (int d = 0; d < 3; ++d)
                #pragma unroll
                for (int k = 0; k < 4; ++k)
                    *(unsigned*)(L2 + (d * 20 + 4 * g + k) * LP + jl) =
                        pack2bf(pa[d] * ea[k], pb[d] * eb[k]);
            if (g < 3) {    // q4 rows e=16..19 for d=g
                const float4 ca = *(const float4*)(expansion + jg * 20 + 16);
                const float4 cb = *(const float4*)(expansion + (jg + 1) * 20 + 16);
                const float sa = (g == 0) ? pa[0] : ((g == 1) ? pa[1] : pa[2]);
                const float sb = (g == 0) ? pb[0] : ((g == 1) ? pb[1] : pb[2]);
                const float ea4[4] = {ca.x, ca.y, ca.z, ca.w};
                const float eb4[4] = {cb.x, cb.y, cb.z, cb.w};
                #pragma unroll
                for (int k = 0; k < 4; ++k)
                    *(unsigned*)(L2 + (g * 20 + 16 + k) * LP + jl) =
                        pack2bf(sa * ea4[k], sb * eb4[k]);
            } else {        // rows 60..62: m*dir_d
                #pragma unroll
                for (int d = 0; d < 3; ++d)
                    *(unsigned*)(L2 + (60 + d) * LP + jl) = pack2bf(pa[d], pb[d]);
            }

            const int koff = quad * 8;
            const v8s c0 = *(const v8s*)(L2 + (lrow) * LP + koff);
            const v8s c1 = *(const v8s*)(L2 + (16 + lrow) * LP + koff);
            const v8s c2 = *(const v8s*)(L2 + (32 + lrow) * LP + koff);
            const v8s c3 = *(const v8s*)(L2 + (48 + lrow) * LP + koff);
            const unsigned short* Bp = RT + (size_t)(128 + lrow) * NN + j0 + koff;
            const v8s b0 = *(const v8s*)(Bp);
            const v8s b1 = *(const v8s*)(Bp + (size_t)16 * NN);
            acc[0] = MFMA(c0, b0, acc[0]); acc[1] = MFMA(c0, b1, acc[1]);
            acc[2] = MFMA(c1, b0, acc[2]); acc[3] = MFMA(c1, b1, acc[3]);
            acc[4] = MFMA(c2, b0, acc[4]); acc[5] = MFMA(c2, b1, acc[5]);
            acc[6] = MFMA(c3, b0, acc[6]); acc[7] = MFMA(c3, b1, acc[7]);
        }
    }

    __syncthreads();   // L buffers dead; safe to overlay T
    if (wave == 0) {
        #pragma unroll
        for (int mt = 0; mt < 2; ++mt)
        #pragma unroll
        for (int nt = 0; nt < 8; ++nt)
        #pragma unroll
        for (int r = 0; r < 4; ++r) {
            const int row = mt * 16 + quad * 4 + r;
            if (row <= 20) T1c[row * 128 + nt * 16 + lrow] = acc[mt * 8 + nt][r];
        }
    } else {
        #pragma unroll
        for (int mt = 0; mt < 4; ++mt)
        #pragma unroll
        for (int nb = 0; nb < 2; ++nb)
        #pragma unroll
        for (int r = 0; r < 4; ++r) {
            const int row = mt * 16 + quad * 4 + r;
            if (row <= 62) T2c[row * 32 + nb * 16 + lrow] = acc[mt * 2 + nb][r];
        }
    }
    __syncthreads();

    // ---- epilogue: contract T with mR_w/mR_b (proven in round 4) ----
    if (t < 32) {
        const int f = t;
        float a = mR_b[32 + f] * T1c[20 * 128 + f];
        #pragma unroll
        for (int e = 0; e < 20; ++e) a = fmaf(mR_w[e * 96 + 32 + f], T1c[e * 128 + f], a);
        snew[f] = scalar[i * 32 + f] + a;
    } else if (t < 128) {
        const int q = t - 32, d = q >> 5, f = q & 31;
        const int col = 32 + q;
        float a = mR_b[f] * T1c[20 * 128 + col];
        #pragma unroll
        for (int e = 0; e < 20; ++e) a = fmaf(mR_w[e * 96 + f], T1c[e * 128 + col], a);
        float c = mR_b[64 + f] * T2c[(60 + d) * 32 + f];
        #pragma unroll
        for (int e = 0; e < 20; ++e) c = fmaf(mR_w[e * 96 + 64 + f], T2c[(d * 20 + e) * 32 + f], c);
        vnew[q] = vector[i * 96 + q] + a + c;
    }
    __syncthreads();

    // ---- update phase ----
    if (t < 96) {
        const int d = t >> 5, f = t & 31;
        float au = 0.f, av = 0.f;
        #pragma unroll
        for (int k = 0; k < 32; ++k) {
            const float vv = vnew[d * 32 + k];
            au = fmaf(vv, U_w[k * 32 + f], au);
            av = fmaf(vv, V_w[k * 32 + f], av);
        }
        lUs[t] = au; rVs[t] = av;
    }
    __syncthreads();
    if (t < 32)
        rnorm[t] = sqrtf(rVs[t] * rVs[t] + rVs[32 + t] * rVs[32 + t] + rVs[64 + t] * rVs[64 + t]);
    __syncthreads();
    if (t < 32) {
        float a = uR_b1[t];
        #pragma unroll
        for (int k = 0; k < 32; ++k) a = fmaf(snew[k], uR_w1[k * 32 + t], a);
        #pragma unroll
        for (int k = 0; k < 32; ++k) a = fmaf(rnorm[k], uR_w1[(32 + k) * 32 + t], a);
        h2s[t] = silu_f(a);
    }
    __syncthreads();
    if (t < 96) {
        float a = uR_b2[t];
        #pragma unroll
        for (int k = 0; k < 32; ++k) a = fmaf(h2s[k], uR_w2[k * 96 + t], a);
        f2s[t] = a;
    }
    __syncthreads();
    if (t < 32) {
        const float inner = lUs[t] * rVs[t] + lUs[32 + t] * rVs[32 + t] + lUs[64 + t] * rVs[64 + t];
        out[i * 32 + t] = snew[t] + inner * f2s[32 + t] + f2s[64 + t];
    }
    if (t < 96) {
        out[32768 + i * 96 + t] = vnew[t] + f2s[t & 31] * lUs[t];
    }
}

extern "C" void kernel_launch(void* const* d_in, const int* in_sizes, int n_in,
                              void* d_out, int out_size, void* d_ws, size_t ws_size,
                              hipStream_t stream) {
    const float* scalar    = (const float*)d_in[0];
    const float* vector    = (const float*)d_in[1];
    const float* expansion = (const float*)d_in[2];
    const float* direction = (const float*)d_in[3];
    const float* mask      = (const float*)d_in[4];
    const float* mL_w1     = (const float*)d_in[5];
    const float* mL_b1     = (const float*)d_in[6];
    const float* mL_w2     = (const float*)d_in[7];
    const float* mL_b2     = (const float*)d_in[8];
    const float* mR_w      = (const float*)d_in[9];
    const float* mR_b      = (const float*)d_in[10];
    const float* uR_w1     = (const float*)d_in[11];
    const float* uR_b1     = (const float*)d_in[12];
    const float* uR_w2     = (const float*)d_in[13];
    const float* uR_b2     = (const float*)d_in[14];
    const float* U_w       = (const float*)d_in[15];
    const float* V_w       = (const float*)d_in[16];
    float* out = (float*)d_out;
    unsigned short* RT = (unsigned short*)d_ws;   // 160*1024*2 = 320 KB

    hipLaunchKernelGGL(node_kernel, dim3(NN), dim3(128), 0, stream,
                       scalar, vector, mL_w1, mL_b1, mL_w2, mL_b2, RT);
    hipLaunchKernelGGL(edge_mfma_kernel, dim3(NN), dim3(128), 0, stream,
                       scalar, vector, expansion, direction, mask,
                       mR_w, mR_b, uR_w1, uR_b1, uR_w2, uR_b2, U_w, V_w,
                       RT, out);
}

// Round 6
// 215.975 us; speedup vs baseline: 1.0641x; 1.0641x over previous
//
#include <hip/hip_runtime.h>
#include <hip/hip_bf16.h>
#include <math.h>

#define NN 1024
#define KJ 32                 // j per chunk
#define NCHUNK (NN / KJ)      // 32
#define HCH (NCHUNK / 2)      // 16 chunks per wave (K-split)
#define LP 40                 // LDS row pitch in ushorts (80 B)

typedef __attribute__((ext_vector_type(8))) short v8s;
typedef __attribute__((ext_vector_type(4))) float v4f;

#define MFMA(a, b, c) __builtin_amdgcn_mfma_f32_16x16x32_bf16((a), (b), (c), 0, 0, 0)

static __device__ __forceinline__ float silu_f(float x) {
    return x / (1.0f + __expf(-x));
}
static __device__ __forceinline__ unsigned short f2bf(float x) {
    __hip_bfloat16 h = __float2bfloat16(x);
    unsigned short u; __builtin_memcpy(&u, &h, 2); return u;
}
static __device__ __forceinline__ unsigned pack2bf(float lo, float hi) {
    __hip_bfloat162 h = __float22bfloat162_rn(make_float2(lo, hi));
    unsigned u; __builtin_memcpy(&u, &h, 4); return u;
}

// ---------------------------------------------------------------------------
// Kernel 1: per-node precompute -> RT[160][1024] bf16 (n-major, j contiguous).
// rows 0..31: lB[f]; 32..127: P[d,f]=v[j,d,f]*lA[f]; 128..159: lC[f].
// ---------------------------------------------------------------------------
extern "C" __global__ __launch_bounds__(128)
void node_kernel(const float* __restrict__ scalar,
                 const float* __restrict__ vector,
                 const float* __restrict__ mL_w1, const float* __restrict__ mL_b1,
                 const float* __restrict__ mL_w2, const float* __restrict__ mL_b2,
                 unsigned short* __restrict__ RT)
{
    const int j = blockIdx.x;
    const int t = threadIdx.x;
    __shared__ float ss[32], sh[32], sleft[96];

    if (t < 32) ss[t] = scalar[j * 32 + t];
    __syncthreads();
    if (t < 32) {
        float a = mL_b1[t];
        #pragma unroll
        for (int k = 0; k < 32; k++) a = fmaf(ss[k], mL_w1[k * 32 + t], a);
        sh[t] = silu_f(a);
    }
    __syncthreads();
    if (t < 96) {
        float a = mL_b2[t];
        #pragma unroll
        for (int k = 0; k < 32; k++) a = fmaf(sh[k], mL_w2[k * 96 + t], a);
        sleft[t] = a;
    }
    __syncthreads();
    for (int n = t; n < 160; n += 128) {
        float val;
        if (n < 32)        val = sleft[32 + n];
        else if (n < 128)  val = vector[j * 96 + (n - 32)] * sleft[(n - 32) & 31];
        else               val = sleft[64 + (n - 128)];
        RT[(size_t)n * NN + j] = f2bf(val);
    }
}

// ---------------------------------------------------------------------------
// Kernel 2: 4-wave K-split MFMA + register prefetch + fused epilogue. 1 blk/i.
// waves 0,1: T1 halves; waves 2,3: T2 halves. Private L buffers, no barriers
// in the main loop.
// ---------------------------------------------------------------------------
extern "C" __global__ __launch_bounds__(256, 4)
void edge_mfma_kernel(const float* __restrict__ scalar,
                      const float* __restrict__ vector,
                      const float* __restrict__ expansion,
                      const float* __restrict__ direction,
                      const float* __restrict__ mask,
                      const float* __restrict__ mR_w, const float* __restrict__ mR_b,
                      const float* __restrict__ uR_w1, const float* __restrict__ uR_b1,
                      const float* __restrict__ uR_w2, const float* __restrict__ uR_b2,
                      const float* __restrict__ U_w,  const float* __restrict__ V_w,
                      const unsigned short* __restrict__ RT,
                      float* __restrict__ out)
{
    const int i = blockIdx.x;
    const int t = threadIdx.x;
    const int wave = t >> 6;
    const int lane = t & 63;
    const int lrow = lane & 15;
    const int quad = lane >> 4;
    const int jp = lane >> 2;      // 0..15 (j-pair slot)
    const int g  = lane & 3;       // row-group
    const int jl = jp * 2;
    const int half = wave & 1;

    // smem: L buffers (bf16) overlaid by compact T (fp32) after the main loop
    __shared__ __align__(16) char smem[18944];
    // L1 half0 @0 (2560B), half1 @2560; L2 half0 @5120 (5120B), half1 @10240
    unsigned short* L1 = (unsigned short*)smem + half * (32 * LP);
    unsigned short* L2 = (unsigned short*)(smem + 5120) + half * (64 * LP);
    float* T1c = (float*)smem;                    // [21][128] = 10752B
    float* T2c = (float*)(smem + 10752);          // [63][32]  =  8064B
    __shared__ float snew[32], vnew[96], lUs[96], rVs[96], rnorm[32], h2s[32], f2s[96];

    v4f acc[16];
    #pragma unroll
    for (int q = 0; q < 16; ++q) acc[q] = (v4f){0.f, 0.f, 0.f, 0.f};

    const int ch0 = half * HCH;
    const int chEnd = ch0 + HCH;

    if (wave < 2) {
        // ---- T1 waves: L1 rows = m*exp (e=0..19), row 20 = m ----
        float4 fa, fb, ca, cb; float m0, m1;
        {
            const size_t jg = (size_t)i * NN + ch0 * KJ + jl;
            fa = *(const float4*)(expansion + jg * 20 + 4 * g);
            fb = *(const float4*)(expansion + (jg + 1) * 20 + 4 * g);
            m0 = mask[jg]; m1 = mask[jg + 1];
            if (g == 3) {
                ca = *(const float4*)(expansion + jg * 20 + 16);
                cb = *(const float4*)(expansion + (jg + 1) * 20 + 16);
            } else { ca = fa; cb = fb; }
        }
        for (int ch = ch0; ch < chEnd; ++ch) {
            // prefetch next chunk (clamped)
            float4 nfa, nfb, nca, ncb; float nm0, nm1;
            {
                const int pch = (ch + 1 < chEnd) ? (ch + 1) : ch;
                const size_t jg = (size_t)i * NN + pch * KJ + jl;
                nfa = *(const float4*)(expansion + jg * 20 + 4 * g);
                nfb = *(const float4*)(expansion + (jg + 1) * 20 + 4 * g);
                nm0 = mask[jg]; nm1 = mask[jg + 1];
                if (g == 3) {
                    nca = *(const float4*)(expansion + jg * 20 + 16);
                    ncb = *(const float4*)(expansion + (jg + 1) * 20 + 16);
                } else { nca = nfa; ncb = nfb; }
            }
            // pack current into L1
            {
                const float ea[4] = {fa.x, fa.y, fa.z, fa.w};
                const float eb[4] = {fb.x, fb.y, fb.z, fb.w};
                #pragma unroll
                for (int k = 0; k < 4; ++k)
                    *(unsigned*)(L1 + (4 * g + k) * LP + jl) = pack2bf(m0 * ea[k], m1 * eb[k]);
            }
            if (g == 3) {
                const float ea[4] = {ca.x, ca.y, ca.z, ca.w};
                const float eb[4] = {cb.x, cb.y, cb.z, cb.w};
                #pragma unroll
                for (int k = 0; k < 4; ++k)
                    *(unsigned*)(L1 + (16 + k) * LP + jl) = pack2bf(m0 * ea[k], m1 * eb[k]);
            }
            if (g == 0) *(unsigned*)(L1 + 20 * LP + jl) = pack2bf(m0, m1);

            // MFMA
            const int j0 = ch * KJ;
            const int koff = quad * 8;
            const v8s a0 = *(const v8s*)(L1 + lrow * LP + koff);
            const v8s a1 = *(const v8s*)(L1 + (16 + lrow) * LP + koff);
            const unsigned short* Bp = RT + (size_t)lrow * NN + j0 + koff;
            #pragma unroll
            for (int nt = 0; nt < 8; ++nt) {
                const v8s b = *(const v8s*)(Bp + (size_t)nt * 16 * NN);
                acc[nt]     = MFMA(a0, b, acc[nt]);
                acc[8 + nt] = MFMA(a1, b, acc[8 + nt]);
            }
            fa = nfa; fb = nfb; ca = nca; cb = ncb; m0 = nm0; m1 = nm1;
        }
    } else {
        // ---- T2 waves: L2 rows d*20+e = m*dir_d*exp_e, rows 60..62 = m*dir_d ----
        float4 fa, fb, ca, cb; float m0, m1, da0, da1, da2, db0, db1, db2;
        {
            const size_t jg = (size_t)i * NN + ch0 * KJ + jl;
            fa = *(const float4*)(expansion + jg * 20 + 4 * g);
            fb = *(const float4*)(expansion + (jg + 1) * 20 + 4 * g);
            m0 = mask[jg]; m1 = mask[jg + 1];
            da0 = direction[jg * 3 + 0]; da1 = direction[jg * 3 + 1]; da2 = direction[jg * 3 + 2];
            db0 = direction[(jg + 1) * 3 + 0]; db1 = direction[(jg + 1) * 3 + 1]; db2 = direction[(jg + 1) * 3 + 2];
            if (g < 3) {
                ca = *(const float4*)(expansion + jg * 20 + 16);
                cb = *(const float4*)(expansion + (jg + 1) * 20 + 16);
            } else { ca = fa; cb = fb; }
        }
        for (int ch = ch0; ch < chEnd; ++ch) {
            float4 nfa, nfb, nca, ncb; float nm0, nm1, nda0, nda1, nda2, ndb0, ndb1, ndb2;
            {
                const int pch = (ch + 1 < chEnd) ? (ch + 1) : ch;
                const size_t jg = (size_t)i * NN + pch * KJ + jl;
                nfa = *(const float4*)(expansion + jg * 20 + 4 * g);
                nfb = *(const float4*)(expansion + (jg + 1) * 20 + 4 * g);
                nm0 = mask[jg]; nm1 = mask[jg + 1];
                nda0 = direction[jg * 3 + 0]; nda1 = direction[jg * 3 + 1]; nda2 = direction[jg * 3 + 2];
                ndb0 = direction[(jg + 1) * 3 + 0]; ndb1 = direction[(jg + 1) * 3 + 1]; ndb2 = direction[(jg + 1) * 3 + 2];
                if (g < 3) {
                    nca = *(const float4*)(expansion + jg * 20 + 16);
                    ncb = *(const float4*)(expansion + (jg + 1) * 20 + 16);
                } else { nca = nfa; ncb = nfb; }
            }
            {
                const float pa[3] = {m0 * da0, m0 * da1, m0 * da2};
                const float pb[3] = {m1 * db0, m1 * db1, m1 * db2};
                const float ea[4] = {fa.x, fa.y, fa.z, fa.w};
                const float eb[4] = {fb.x, fb.y, fb.z, fb.w};
                #pragma unroll
                for (int d = 0; d < 3; ++d)
                    #pragma unroll
                    for (int k = 0; k < 4; ++k)
                        *(unsigned*)(L2 + (d * 20 + 4 * g + k) * LP + jl) =
                            pack2bf(pa[d] * ea[k], pb[d] * eb[k]);
                if (g < 3) {
                    const float sa = (g == 0) ? pa[0] : ((g == 1) ? pa[1] : pa[2]);
                    const float sb = (g == 0) ? pb[0] : ((g == 1) ? pb[1] : pb[2]);
                    const float ea4[4] = {ca.x, ca.y, ca.z, ca.w};
                    const float eb4[4] = {cb.x, cb.y, cb.z, cb.w};
                    #pragma unroll
                    for (int k = 0; k < 4; ++k)
                        *(unsigned*)(L2 + (g * 20 + 16 + k) * LP + jl) =
                            pack2bf(sa * ea4[k], sb * eb4[k]);
                } else {
                    #pragma unroll
                    for (int d = 0; d < 3; ++d)
                        *(unsigned*)(L2 + (60 + d) * LP + jl) = pack2bf(pa[d], pb[d]);
                }
            }
            const int j0 = ch * KJ;
            const int koff = quad * 8;
            const v8s c0 = *(const v8s*)(L2 + (lrow) * LP + koff);
            const v8s c1 = *(const v8s*)(L2 + (16 + lrow) * LP + koff);
            const v8s c2 = *(const v8s*)(L2 + (32 + lrow) * LP + koff);
            const v8s c3 = *(const v8s*)(L2 + (48 + lrow) * LP + koff);
            const unsigned short* Bp = RT + (size_t)(128 + lrow) * NN + j0 + koff;
            const v8s b0 = *(const v8s*)(Bp);
            const v8s b1 = *(const v8s*)(Bp + (size_t)16 * NN);
            acc[0] = MFMA(c0, b0, acc[0]); acc[1] = MFMA(c0, b1, acc[1]);
            acc[2] = MFMA(c1, b0, acc[2]); acc[3] = MFMA(c1, b1, acc[3]);
            acc[4] = MFMA(c2, b0, acc[4]); acc[5] = MFMA(c2, b1, acc[5]);
            acc[6] = MFMA(c3, b0, acc[6]); acc[7] = MFMA(c3, b1, acc[7]);
            fa = nfa; fb = nfb; ca = nca; cb = ncb; m0 = nm0; m1 = nm1;
            da0 = nda0; da1 = nda1; da2 = nda2; db0 = ndb0; db1 = ndb1; db2 = ndb2;
        }
    }

    __syncthreads();   // all L buffers dead; safe to overlay T
    // dump: waves 0,2 store; then waves 1,3 add
    if (wave == 0) {
        #pragma unroll
        for (int mt = 0; mt < 2; ++mt)
        #pragma unroll
        for (int nt = 0; nt < 8; ++nt)
        #pragma unroll
        for (int r = 0; r < 4; ++r) {
            const int row = mt * 16 + quad * 4 + r;
            if (row <= 20) T1c[row * 128 + nt * 16 + lrow] = acc[mt * 8 + nt][r];
        }
    } else if (wave == 2) {
        #pragma unroll
        for (int mt = 0; mt < 4; ++mt)
        #pragma unroll
        for (int nb = 0; nb < 2; ++nb)
        #pragma unroll
        for (int r = 0; r < 4; ++r) {
            const int row = mt * 16 + quad * 4 + r;
            if (row <= 62) T2c[row * 32 + nb * 16 + lrow] = acc[mt * 2 + nb][r];
        }
    }
    __syncthreads();
    if (wave == 1) {
        #pragma unroll
        for (int mt = 0; mt < 2; ++mt)
        #pragma unroll
        for (int nt = 0; nt < 8; ++nt)
        #pragma unroll
        for (int r = 0; r < 4; ++r) {
            const int row = mt * 16 + quad * 4 + r;
            if (row <= 20) T1c[row * 128 + nt * 16 + lrow] += acc[mt * 8 + nt][r];
        }
    } else if (wave == 3) {
        #pragma unroll
        for (int mt = 0; mt < 4; ++mt)
        #pragma unroll
        for (int nb = 0; nb < 2; ++nb)
        #pragma unroll
        for (int r = 0; r < 4; ++r) {
            const int row = mt * 16 + quad * 4 + r;
            if (row <= 62) T2c[row * 32 + nb * 16 + lrow] += acc[mt * 2 + nb][r];
        }
    }
    __syncthreads();

    // ---- epilogue: contract T with mR_w/mR_b (verified round 4) ----
    if (t < 32) {
        const int f = t;
        float a = mR_b[32 + f] * T1c[20 * 128 + f];
        #pragma unroll
        for (int e = 0; e < 20; ++e) a = fmaf(mR_w[e * 96 + 32 + f], T1c[e * 128 + f], a);
        snew[f] = scalar[i * 32 + f] + a;
    } else if (t < 128) {
        const int q = t - 32, d = q >> 5, f = q & 31;
        const int col = 32 + q;
        float a = mR_b[f] * T1c[20 * 128 + col];
        #pragma unroll
        for (int e = 0; e < 20; ++e) a = fmaf(mR_w[e * 96 + f], T1c[e * 128 + col], a);
        float c = mR_b[64 + f] * T2c[(60 + d) * 32 + f];
        #pragma unroll
        for (int e = 0; e < 20; ++e) c = fmaf(mR_w[e * 96 + 64 + f], T2c[(d * 20 + e) * 32 + f], c);
        vnew[q] = vector[i * 96 + q] + a + c;
    }
    __syncthreads();

    // ---- update phase ----
    if (t < 96) {
        const int d = t >> 5, f = t & 31;
        float au = 0.f, av = 0.f;
        #pragma unroll
        for (int k = 0; k < 32; ++k) {
            const float vv = vnew[d * 32 + k];
            au = fmaf(vv, U_w[k * 32 + f], au);
            av = fmaf(vv, V_w[k * 32 + f], av);
        }
        lUs[t] = au; rVs[t] = av;
    }
    __syncthreads();
    if (t < 32)
        rnorm[t] = sqrtf(rVs[t] * rVs[t] + rVs[32 + t] * rVs[32 + t] + rVs[64 + t] * rVs[64 + t]);
    __syncthreads();
    if (t < 32) {
        float a = uR_b1[t];
        #pragma unroll
        for (int k = 0; k < 32; ++k) a = fmaf(snew[k], uR_w1[k * 32 + t], a);
        #pragma unroll
        for (int k = 0; k < 32; ++k) a = fmaf(rnorm[k], uR_w1[(32 + k) * 32 + t], a);
        h2s[t] = silu_f(a);
    }
    __syncthreads();
    if (t < 96) {
        float a = uR_b2[t];
        #pragma unroll
        for (int k = 0; k < 32; ++k) a = fmaf(h2s[k], uR_w2[k * 96 + t], a);
        f2s[t] = a;
    }
    __syncthreads();
    if (t < 32) {
        const float inner = lUs[t] * rVs[t] + lUs[32 + t] * rVs[32 + t] + lUs[64 + t] * rVs[64 + t];
        out[i * 32 + t] = snew[t] + inner * f2s[32 + t] + f2s[64 + t];
    }
    if (t < 96) {
        out[32768 + i * 96 + t] = vnew[t] + f2s[t & 31] * lUs[t];
    }
}

extern "C" void kernel_launch(void* const* d_in, const int* in_sizes, int n_in,
                              void* d_out, int out_size, void* d_ws, size_t ws_size,
                              hipStream_t stream) {
    const float* scalar    = (const float*)d_in[0];
    const float* vector    = (const float*)d_in[1];
    const float* expansion = (const float*)d_in[2];
    const float* direction = (const float*)d_in[3];
    const float* mask      = (const float*)d_in[4];
    const float* mL_w1     = (const float*)d_in[5];
    const float* mL_b1     = (const float*)d_in[6];
    const float* mL_w2     = (const float*)d_in[7];
    const float* mL_b2     = (const float*)d_in[8];
    const float* mR_w      = (const float*)d_in[9];
    const float* mR_b      = (const float*)d_in[10];
    const float* uR_w1     = (const float*)d_in[11];
    const float* uR_b1     = (const float*)d_in[12];
    const float* uR_w2     = (const float*)d_in[13];
    const float* uR_b2     = (const float*)d_in[14];
    const float* U_w       = (const float*)d_in[15];
    const float* V_w       = (const float*)d_in[16];
    float* out = (float*)d_out;
    unsigned short* RT = (unsigned short*)d_ws;   // 160*1024*2 = 320 KB

    hipLaunchKernelGGL(node_kernel, dim3(NN), dim3(128), 0, stream,
                       scalar, vector, mL_w1, mL_b1, mL_w2, mL_b2, RT);
    hipLaunchKernelGGL(edge_mfma_kernel, dim3(NN), dim3(256), 0, stream,
                       scalar, vector, expansion, direction, mask,
                       mR_w, mR_b, uR_w1, uR_b1, uR_w2, uR_b2, U_w, V_w,
                       RT, out);
}